// Round 2
// baseline (1012.995 us; speedup 1.0000x reference)
//
#include <hip/hip_runtime.h>
#include <cstdint>

static constexpr int Ln = 1024;   // nodes
static constexpr int Cn = 16;     // in channels
static constexpr int On = 64;     // out channels
static constexpr int W1K = 15 * Cn; // 240

// ---- workspace layout (float offsets) ----
static constexpr size_t WS_COL  = 0;                        // [L][C]  col_sum[i,c] = sum_j Tm[i,j,c]
static constexpr size_t WS_ROW  = WS_COL  + (size_t)Ln*Cn;  // [L][C]  row_sum[j,c] = sum_i Tm[i,j,c]
static constexpr size_t WS_DIAG = WS_ROW  + (size_t)Ln*Cn;  // [L][C]
static constexpr size_t WS_TR   = WS_DIAG + (size_t)Ln*Cn;  // [C]
static constexpr size_t WS_ALL  = WS_TR   + Cn;             // [C]
static constexpr size_t WS_C0   = WS_ALL  + Cn;             // [O]
static constexpr size_t WS_A    = WS_C0   + On;             // [L][O] terms depending on j
static constexpr size_t WS_B    = WS_A    + (size_t)Ln*On;  // [L][O] terms depending on i
static constexpr size_t WS_D    = WS_B    + (size_t)Ln*On;  // [L][O] diagonal-only terms
static constexpr size_t WS_W7T  = WS_D    + (size_t)Ln*On;  // [C][O] W1 block 6 (transpose term)
static constexpr size_t WS_W8T  = WS_W7T  + (size_t)Cn*On;  // [C][O] W1 block 7 (identity term)
static constexpr size_t WS_RPART= WS_W8T  + (size_t)Cn*On;  // [16][L][C] row_sum partials

__device__ __forceinline__ float4 masked4(const float* __restrict__ tp,
                                          const int* __restrict__ mp) {
  float4 t = *(const float4*)tp;
  int4  m = *(const int4*)mp;
  float4 r;
  r.x = m.x ? t.x : 0.f;
  r.y = m.y ? t.y : 0.f;
  r.z = m.z ? t.z : 0.f;
  r.w = m.w ? t.w : 0.f;
  return r;
}

// col_sum[i,c] = sum_j Tm[i,j,c]; also extracts diag. One block per row i. Coalesced.
__global__ __launch_bounds__(256) void k_colsum_diag(const float* __restrict__ T,
                                                     const int* __restrict__ Mk,
                                                     float* __restrict__ ws) {
  const int i = blockIdx.x;
  const int t = threadIdx.x;
  const float* rowT = T  + (size_t)i * Ln * Cn;
  const int*   rowM = Mk + (size_t)i * Ln * Cn;
  float s[Cn];
#pragma unroll
  for (int c = 0; c < Cn; c++) s[c] = 0.f;
  for (int j = t; j < Ln; j += 256) {
#pragma unroll
    for (int q = 0; q < 4; q++) {
      float4 v = masked4(rowT + j * Cn + q * 4, rowM + j * Cn + q * 4);
      s[q*4+0] += v.x; s[q*4+1] += v.y; s[q*4+2] += v.z; s[q*4+3] += v.w;
      if (j == i) {
        float* dg = ws + WS_DIAG + (size_t)i * Cn + q * 4;
        dg[0] = v.x; dg[1] = v.y; dg[2] = v.z; dg[3] = v.w;
      }
    }
  }
  __shared__ float red[256][Cn + 1];
#pragma unroll
  for (int c = 0; c < Cn; c++) red[t][c] = s[c];
  __syncthreads();
  for (int off = 128; off > 0; off >>= 1) {
    if (t < off) {
#pragma unroll
      for (int c = 0; c < Cn; c++) red[t][c] += red[t + off][c];
    }
    __syncthreads();
  }
  if (t < Cn) ws[WS_COL + (size_t)i * Cn + t] = red[0][t];
}

// Coalesced row_sum partials: block (bj, bi) handles 64 cols x 64-row band.
// Lane t reads base + t*16B => contiguous 4KB per wave op.
__global__ __launch_bounds__(256) void k_rowsum_part(const float* __restrict__ T,
                                                     const int* __restrict__ Mk,
                                                     float* __restrict__ ws) {
  const int bj = blockIdx.x, bi = blockIdx.y, t = threadIdx.x;
  const int jl = t >> 2, c4 = t & 3;
  const int j = bj * 64 + jl;
  float4 acc = {0.f, 0.f, 0.f, 0.f};
  for (int ii = 0; ii < 64; ii++) {
    const int i = bi * 64 + ii;
    const size_t base = ((size_t)i * Ln + j) * Cn + c4 * 4;
    float4 v = masked4(T + base, Mk + base);
    acc.x += v.x; acc.y += v.y; acc.z += v.z; acc.w += v.w;
  }
  *(float4*)(ws + WS_RPART + ((size_t)bi * Ln + j) * Cn + c4 * 4) = acc;
}

__global__ __launch_bounds__(256) void k_rowsum_reduce(float* __restrict__ ws) {
  const int idx = blockIdx.x * 256 + threadIdx.x;  // 16384 = 1024*16
  const int j = idx >> 4, c = idx & 15;
  float s = 0.f;
#pragma unroll
  for (int p = 0; p < 16; p++)
    s += ws[WS_RPART + ((size_t)p * Ln + j) * Cn + c];
  ws[WS_ROW + (size_t)j * Cn + c] = s;
}

// trace, all_sum, c0, transposed W7/W8 blocks. Single block.
__global__ __launch_bounds__(256) void k_scalars(const float* __restrict__ W1,
                                                 const float* __restrict__ b1,
                                                 float* __restrict__ ws) {
  const int t = threadIdx.x;
  __shared__ float redt[16][17], reda[16][17];
  __shared__ float trs[Cn], als[Cn];

  for (int idx = t; idx < 2 * Cn * On; idx += 256) {
    int which = idx >> 10;      // Cn*On == 1024
    int rem = idx & 1023;
    int c = rem >> 6, o = rem & 63;
    ws[(which ? WS_W8T : WS_W7T) + rem] = W1[o * W1K + (which ? 7 : 6) * Cn + c];
  }
  {
    int c = t & 15, seg = t >> 4;
    float a = 0.f, b = 0.f;
    for (int i = seg * 64; i < seg * 64 + 64; i++) {
      a += ws[WS_DIAG + (size_t)i * Cn + c];
      b += ws[WS_COL  + (size_t)i * Cn + c];
    }
    redt[seg][c] = a;
    reda[seg][c] = b;
  }
  __syncthreads();
  if (t < Cn) {
    float ta = 0.f, tb = 0.f;
    for (int s = 0; s < 16; s++) { ta += redt[s][t]; tb += reda[s][t]; }
    ws[WS_TR + t] = ta; ws[WS_ALL + t] = tb;
    trs[t] = ta; als[t] = tb;
  }
  __syncthreads();
  if (t < On) {
    float acc = b1[t];
#pragma unroll
    for (int c = 0; c < Cn; c++)
      acc += W1[t * W1K + 8 * Cn + c] * trs[c] + W1[t * W1K + 14 * Cn + c] * als[c];
    ws[WS_C0 + t] = acc;
  }
}

// Per-node A/B/D vectors. One block per node, thread = output channel.
__global__ __launch_bounds__(64) void k_node_terms(const float* __restrict__ W1,
                                                   float* __restrict__ ws) {
  const int n = blockIdx.x;
  const int o = threadIdx.x;
  __shared__ float sd[Cn], sr[Cn], sc[Cn], st[Cn], sa[Cn];
  if (o < Cn) {
    sd[o] = ws[WS_DIAG + (size_t)n * Cn + o];
    sr[o] = ws[WS_ROW  + (size_t)n * Cn + o];
    sc[o] = ws[WS_COL  + (size_t)n * Cn + o];
    st[o] = ws[WS_TR + o];
    sa[o] = ws[WS_ALL + o];
  }
  __syncthreads();
  const float* w = W1 + o * W1K;
  float a = 0.f, b = 0.f, d = 0.f;
#pragma unroll
  for (int c = 0; c < Cn; c++) {
    a += w[ 1*Cn + c] * sd[c] + w[ 9*Cn + c] * sr[c] + w[10*Cn + c] * sc[c];
    b += w[ 2*Cn + c] * sd[c] + w[12*Cn + c] * sc[c] + w[13*Cn + c] * sr[c];
    d += w[ 0*Cn + c] * sd[c] + w[ 3*Cn + c] * sr[c] + w[ 4*Cn + c] * sc[c]
       + w[ 5*Cn + c] * st[c] + w[11*Cn + c] * sa[c];
  }
  ws[WS_A + (size_t)n * On + o] = a;
  ws[WS_B + (size_t)n * On + o] = b;
  ws[WS_D + (size_t)n * On + o] = d;
}

// Main fused kernel: pair-tile block. Block (I,J), J>=I, 512 threads.
// Half 0 computes out[I-tile, J-tile], half 1 computes out[J-tile, I-tile].
// Both T tiles staged via LDS with coalesced global loads.
__global__ __launch_bounds__(512, 4) void k_main(const float* __restrict__ T,
                                                 const int* __restrict__ Mk,
                                                 const float* __restrict__ W2,
                                                 const float* __restrict__ b2,
                                                 const float* __restrict__ ws,
                                                 float* __restrict__ out) {
  const int I = blockIdx.y, J = blockIdx.x;
  if (J < I) return;
  const int t = threadIdx.x;
  const int half = t >> 8, tl = t & 255;

  // plane-major tiles: s?[c*256 + r*16 + col]
  __shared__ float sA[16 * 256];   // sA[c][ra*16+ca]  = Tm[I*16+ra, J*16+ca, c]
  __shared__ float sB[16 * 256];   // sB[c][ca*16+rb]  = Tm[J*16+rb, I*16+ca, c]
  __shared__ float nAJ[16 * 65], nBI[16 * 65], nAI[16 * 65], nBJ[16 * 65];

  // ---- stage T tiles (mask applied here) ----
#pragma unroll
  for (int k = 0; k < 2; k++) {
    const int fq = t + k * 512;            // float4 id 0..1023
    const int r = fq >> 6, rem = fq & 63, col = rem >> 2, c4 = rem & 3;
    {
      const size_t g = (((size_t)(I * 16 + r)) * Ln + (J * 16 + col)) * Cn + c4 * 4;
      float4 v = masked4(T + g, Mk + g);
      const int b = r * 16 + col;
      sA[(c4 * 4 + 0) * 256 + b] = v.x;
      sA[(c4 * 4 + 1) * 256 + b] = v.y;
      sA[(c4 * 4 + 2) * 256 + b] = v.z;
      sA[(c4 * 4 + 3) * 256 + b] = v.w;
    }
    {
      const size_t g = (((size_t)(J * 16 + r)) * Ln + (I * 16 + col)) * Cn + c4 * 4;
      float4 v = masked4(T + g, Mk + g);
      const int b = col * 16 + r;          // transposed store
      sB[(c4 * 4 + 0) * 256 + b] = v.x;
      sB[(c4 * 4 + 1) * 256 + b] = v.y;
      sB[(c4 * 4 + 2) * 256 + b] = v.z;
      sB[(c4 * 4 + 3) * 256 + b] = v.w;
    }
  }
  // ---- stage node vectors (A/B for both tiles), padded to 65 ----
#pragma unroll
  for (int k = 0; k < 8; k++) {
    const int f = t + k * 512;             // 0..4095
    const int arr = f >> 10, rem = f & 1023, nl = rem >> 6, o = rem & 63;
    switch (arr) {
      case 0: nAJ[nl * 65 + o] = ws[WS_A + ((size_t)(J * 16 + nl)) * On + o]; break;
      case 1: nBI[nl * 65 + o] = ws[WS_B + ((size_t)(I * 16 + nl)) * On + o]; break;
      case 2: nAI[nl * 65 + o] = ws[WS_A + ((size_t)(I * 16 + nl)) * On + o]; break;
      default: nBJ[nl * 65 + o] = ws[WS_B + ((size_t)(J * 16 + nl)) * On + o]; break;
    }
  }
  __syncthreads();

  const int r = tl >> 4, col = tl & 15;
  const int i = (half ? J : I) * 16 + r;
  const int j = (half ? I : J) * 16 + col;
  const int idx = half ? (col * 16 + r) : tl;
  const float* Pij = half ? sB : sA;
  const float* Pji = half ? sA : sB;
  const float* pA = (half ? nAI : nAJ) + col * 65;
  const float* pB = (half ? nBJ : nBI) + r * 65;
  const float* c0 = ws + WS_C0;

  float v[On];
#pragma unroll
  for (int o = 0; o < On; o++) v[o] = pA[o] + pB[o] + c0[o];
  if (i == j) {
    const float* Di = ws + WS_D + (size_t)i * On;
#pragma unroll
    for (int o = 0; o < On; o++) v[o] += Di[o];
  }

  const float* W7t = ws + WS_W7T;
  const float* W8t = ws + WS_W8T;
#pragma unroll
  for (int c = 0; c < Cn; c++) {
    const float a  = Pji[c * 256 + idx];
    const float bb = Pij[c * 256 + idx];
#pragma unroll
    for (int o = 0; o < On; o++)
      v[o] += W7t[c * On + o] * a + W8t[c * On + o] * bb;
  }

#pragma unroll
  for (int o = 0; o < On; o++) v[o] = fmaxf(v[o], 0.f);

  float* op = out + ((size_t)i * Ln + j) * On;
#pragma unroll
  for (int p4 = 0; p4 < On / 4; p4++) {
    float4 acc;
    acc.x = b2[p4 * 4 + 0];
    acc.y = b2[p4 * 4 + 1];
    acc.z = b2[p4 * 4 + 2];
    acc.w = b2[p4 * 4 + 3];
#pragma unroll
    for (int o = 0; o < On; o++) {
      acc.x += W2[(p4 * 4 + 0) * On + o] * v[o];
      acc.y += W2[(p4 * 4 + 1) * On + o] * v[o];
      acc.z += W2[(p4 * 4 + 2) * On + o] * v[o];
      acc.w += W2[(p4 * 4 + 3) * On + o] * v[o];
    }
    *(float4*)(op + p4 * 4) = acc;
  }
}

extern "C" void kernel_launch(void* const* d_in, const int* in_sizes, int n_in,
                              void* d_out, int out_size, void* d_ws, size_t ws_size,
                              hipStream_t stream) {
  (void)in_sizes; (void)n_in; (void)out_size; (void)ws_size;
  const float* T  = (const float*)d_in[0];
  const int*   Mk = (const int*)d_in[1];
  const float* W1 = (const float*)d_in[2];
  const float* b1 = (const float*)d_in[3];
  const float* W2 = (const float*)d_in[4];
  const float* b2 = (const float*)d_in[5];
  float* out = (float*)d_out;
  float* ws  = (float*)d_ws;

  k_colsum_diag<<<Ln, 256, 0, stream>>>(T, Mk, ws);
  {
    dim3 g(16, 16);
    k_rowsum_part<<<g, 256, 0, stream>>>(T, Mk, ws);
  }
  k_rowsum_reduce<<<64, 256, 0, stream>>>(ws);
  k_scalars<<<1, 256, 0, stream>>>(W1, b1, ws);
  k_node_terms<<<Ln, 64, 0, stream>>>(W1, ws);
  {
    dim3 g(Ln / 16, Ln / 16);
    k_main<<<g, 512, 0, stream>>>(T, Mk, W2, b2, ws, out);
  }
}